// Round 3
// baseline (208.862 us; speedup 1.0000x reference)
//
#include <hip/hip_runtime.h>
#include <hip/hip_bf16.h>
#include <cmath>

#define BB 4
#define NN 2048
#define DIN 128
#define HH 4
#define HD 32
#define KSEL 204            // int(0.1 * 2048)
#define BH (BB*HH)
#define KPAD 256            // K padded to 8 MFMA steps of 32
#define KST 264             // LDS row stride (bf16): 132 words, mod32=4 -> 2-way (free)

typedef __attribute__((ext_vector_type(8))) short short8;
typedef __attribute__((ext_vector_type(4))) short short4v;
typedef __attribute__((ext_vector_type(4))) float float4v;

static __device__ inline short f2bf(float x) {
    __hip_bfloat16 b = __float2bfloat16(x);   // RNE
    return __builtin_bit_cast(short, b);
}

// ---------------------------------------------------------------------------
// K0: h (f32) -> hbf (bf16), coalesced. 1M elems, 4 per thread.
__global__ __launch_bounds__(256) void hcvt_kernel(const float* __restrict__ h,
                                                   short* __restrict__ hbf) {
    int tid = blockIdx.x * 256 + threadIdx.x;
    float4 x = ((const float4*)h)[tid];
    short4v r;
    r[0] = f2bf(x.x); r[1] = f2bf(x.y); r[2] = f2bf(x.z); r[3] = f2bf(x.w);
    *(short4v*)(hbf + (size_t)tid * 4) = r;
}

// ---------------------------------------------------------------------------
// K1: s_i = h.(W@a1), s_j = h.(W@a2)  (all-f32 exact; feeds top-k). Zeroes rank.
__global__ __launch_bounds__(256) void s_kernel(const float* __restrict__ h,
                                                const float* __restrict__ W,
                                                const float* __restrict__ a,
                                                float* __restrict__ si, float* __restrict__ sj,
                                                int* __restrict__ rank) {
    int bh = blockIdx.x >> 3, chunk = blockIdx.x & 7;
    int b = bh >> 2, hh = bh & 3;
    __shared__ float w1[128], w2[128];
    int t = threadIdx.x;
    {   // wa = W[hh] @ a-halves, computed in-block
        int f = t & 127, half = t >> 7;
        const float* Wp = W + (size_t)hh * (DIN * HD) + f * HD;
        const float* ap = a + hh * 64 + half * 32;
        float acc = 0.f;
#pragma unroll
        for (int d = 0; d < 32; ++d) acc += Wp[d] * ap[d];
        if (half == 0) w1[f] = acc; else w2[f] = acc;
    }
    __syncthreads();
    int n = chunk * 256 + t;
    const float4* hr = (const float4*)(h + ((size_t)b * NN + n) * DIN);
    float s1 = 0.f, s2 = 0.f;
#pragma unroll 8
    for (int q = 0; q < 32; ++q) {
        float4 x = hr[q];
        s1 += x.x * w1[q*4] + x.y * w1[q*4+1] + x.z * w1[q*4+2] + x.w * w1[q*4+3];
        s2 += x.x * w2[q*4] + x.y * w2[q*4+1] + x.z * w2[q*4+2] + x.w * w2[q*4+3];
    }
    int o = bh * NN + n;
    si[o] = s1; sj[o] = s2; rank[o] = 0;
}

// ---------------------------------------------------------------------------
// K2: Whg[bh][n][d] (bf16) = hbf[b][n][:] @ W[h][:][d]  via MFMA 16x16x32 bf16
__global__ __launch_bounds__(256) void wh_kernel(const short* __restrict__ hbf,
                                                 const float* __restrict__ W,
                                                 short* __restrict__ Whg) {
    int bh = blockIdx.x >> 4, rtile = blockIdx.x & 15;
    int b = bh >> 2, hh = bh & 3;
    __shared__ short WT[32][136];   // WT[n][k] = bf16(W[hh][k][n])
    int t = threadIdx.x;
    for (int e = t; e < 32 * 128; e += 256) {
        int n = e >> 7, k = e & 127;
        WT[n][k] = f2bf(W[(size_t)hh * (DIN * HD) + k * HD + n]);
    }
    __syncthreads();
    int w = t >> 6, lane = t & 63, mr = lane & 15, quad = lane >> 4;
    int row_base = rtile * 128;
#pragma unroll
    for (int q = 0; q < 4; ++q) {
        int tt = w * 4 + q;
        int rt = tt >> 1, ct = tt & 1;
        int row0 = row_base + rt * 16;
        const short* hrow = hbf + ((size_t)b * NN + row0 + mr) * DIN + quad * 8;
        float4v acc = {0.f, 0.f, 0.f, 0.f};
#pragma unroll
        for (int ks = 0; ks < 4; ++ks) {
            short8 afr = *(const short8*)(hrow + ks * 32);
            short8 bfr = *(const short8*)&WT[ct * 16 + mr][ks * 32 + quad * 8];
            acc = __builtin_amdgcn_mfma_f32_16x16x32_bf16(afr, bfr, acc, 0, 0, 0);
        }
#pragma unroll
        for (int r = 0; r < 4; ++r) {
            int rowg = row0 + quad * 4 + r;
            Whg[((size_t)bh * NN + rowg) * HD + ct * 16 + mr] = f2bf(acc[r]);
        }
    }
}

// ---------------------------------------------------------------------------
// K3: partial rank counts. grid = BH*16; block handles 128 jp's vs all 2048 j's.
__global__ __launch_bounds__(256) void rankp_kernel(const float* __restrict__ sj,
                                                    int* __restrict__ rank) {
    int bh = blockIdx.x >> 4, jpc = blockIdx.x & 15;
    __shared__ float sv[128];
    int t = threadIdx.x;
    if (t < 128) sv[t] = sj[bh * NN + jpc * 128 + t];
    __syncthreads();
    int j0 = t * 8;
    const float* sjb = sj + bh * NN;
    float v[8]; int cnt[8];
#pragma unroll
    for (int r = 0; r < 8; ++r) { v[r] = sjb[j0 + r]; cnt[r] = 0; }
    int jpbase = jpc * 128;
    for (int jp = 0; jp < 128; ++jp) {
        float x = sv[jp];
        int jg = jpbase + jp;
#pragma unroll
        for (int r = 0; r < 8; ++r)
            cnt[r] += (x > v[r]) ? 1 : ((x == v[r] && jg < j0 + r) ? 1 : 0);
    }
#pragma unroll
    for (int r = 0; r < 8; ++r) atomicAdd(&rank[bh * NN + j0 + r], cnt[r]);
}

// ---------------------------------------------------------------------------
// K4: compact selected (rank < KSEL) ascending; sjsel + max; ALSO stage
// Whsel[bh][d][jj] bf16 (zero-padded K to 256) for register B-fragments.
__global__ __launch_bounds__(256) void compact_kernel(const float* __restrict__ sj,
                                                      const int* __restrict__ rank,
                                                      const short* __restrict__ Whg,
                                                      int* __restrict__ idxsel,
                                                      float* __restrict__ sjsel,
                                                      float* __restrict__ sjmax,
                                                      short* __restrict__ Whsel) {
    int bh = blockIdx.x;
    int t = threadIdx.x, lane = t & 63, w = t >> 6;
    const int base = bh * NN;
    __shared__ int idxLDS[KSEL];
    int flags[8], cnt = 0;
    float lmax = -1e30f;
    int j0 = t * 8;
#pragma unroll
    for (int r = 0; r < 8; ++r) {
        int j = j0 + r;
        int f = (rank[base + j] < KSEL) ? 1 : 0;
        flags[r] = f; cnt += f;
        lmax = fmaxf(lmax, sj[base + j]);
    }
    int sc = cnt;
#pragma unroll
    for (int off = 1; off < 64; off <<= 1) {
        int u = __shfl_up(sc, off);
        if (lane >= off) sc += u;
    }
    float mx = lmax;
#pragma unroll
    for (int off = 32; off >= 1; off >>= 1) mx = fmaxf(mx, __shfl_xor(mx, off));
    __shared__ int wtot[4], woff[4];
    __shared__ float wmax[4];
    if (lane == 63) wtot[w] = sc;
    if (lane == 0) wmax[w] = mx;
    __syncthreads();
    if (t == 0) {
        int run = 0;
        for (int i = 0; i < 4; ++i) { woff[i] = run; run += wtot[i]; }
        sjmax[bh] = fmaxf(fmaxf(wmax[0], wmax[1]), fmaxf(wmax[2], wmax[3]));
    }
    __syncthreads();
    int pos = woff[w] + sc - cnt;
#pragma unroll
    for (int r = 0; r < 8; ++r) {
        if (flags[r]) {
            int j = j0 + r;
            idxsel[bh * KSEL + pos] = j;
            sjsel[bh * KSEL + pos] = sj[base + j];
            idxLDS[pos] = j;
            pos++;
        }
    }
    __syncthreads();
    // Whsel[bh][d][jj]: B-operand layout, contiguous jj, zero K-tail
    for (int e = t; e < HD * KPAD; e += 256) {
        int d = e >> 8, jj = e & 255;
        short v = 0;
        if (jj < KSEL) v = Whg[((size_t)bh * NN + idxLDS[jj]) * HD + d];
        Whsel[((size_t)bh * HD + d) * KPAD + jj] = v;
    }
}

// ---------------------------------------------------------------------------
// K5: main attention. Block = (b, 32 rows, ALL 4 heads). adj rows streamed
// contiguously into LDS (8 at a time); per-head gather from LDS; MFMA P@Wh
// with B-fragments in registers. Grid = 4*64 = 256 blocks = 1/CU.
__global__ __launch_bounds__(256) void attn_kernel(
        const float* __restrict__ adj, const short* __restrict__ Whsel,
        const float* __restrict__ si, const int* __restrict__ idxsel,
        const float* __restrict__ sjsel, const float* __restrict__ sjmax,
        float* __restrict__ out) {
    int b = blockIdx.x >> 6, tile = blockIdx.x & 63;
    __shared__ short PS[HH][32][KST];       // P bf16 (exp * adj), K-padded
    __shared__ float adjbuf[8][NN];         // 8 adj rows, dense
    __shared__ int   idxS[HH][208];
    __shared__ float sjS[HH][208];
    __shared__ float invZ[HH][32];
    __shared__ float smaxS[HH];
    int t = threadIdx.x, w = t >> 6, lane = t & 63;
    int mr = lane & 15, quad = lane >> 4;

    // B-fragments for head w into registers (reused all block)
    short8 bfr[2][8];
    {
        const short* wp = Whsel + (size_t)((b * HH + w) * HD) * KPAD;
#pragma unroll
        for (int ni = 0; ni < 2; ++ni)
#pragma unroll
            for (int ks = 0; ks < 8; ++ks)
                bfr[ni][ks] = *(const short8*)(wp + (size_t)(ni * 16 + mr) * KPAD + ks * 32 + quad * 8);
    }
    // stage per-head selection tables
    for (int e = t; e < HH * KSEL; e += 256) {
        int hh = e / KSEL, jj = e - hh * KSEL;
        idxS[hh][jj] = idxsel[(b * HH + hh) * KSEL + jj];
        sjS[hh][jj]  = sjsel[(b * HH + hh) * KSEL + jj];
    }
    if (t < HH) smaxS[t] = sjmax[b * HH + t];
    // zero PS K-tail [KSEL, KPAD)
    for (int e = t; e < HH * 32 * (KPAD - KSEL); e += 256) {
        int jj = KSEL + e % (KPAD - KSEL);
        int r  = (e / (KPAD - KSEL)) & 31;
        int hh = e / ((KPAD - KSEL) * 32);
        PS[hh][r][jj] = 0;
    }
    __syncthreads();

    const float* adjb = adj + (size_t)b * NN * NN;
    int i_base = tile * 32;
    // Phase 1: 4 stages of 8 rows
    for (int s = 0; s < 4; ++s) {
        // cooperative dense load of 8 adj rows
        int i0 = i_base + s * 8;
        for (int e = t; e < 8 * 512; e += 256) {
            int row = e >> 9, c4 = e & 511;
            *(float4*)&adjbuf[row][c4 * 4] =
                *(const float4*)(adjb + (size_t)(i0 + row) * NN + c4 * 4);
        }
        __syncthreads();
        // wave w: rows w*2, w*2+1 of this stage; all 4 heads
#pragma unroll
        for (int r2 = 0; r2 < 2; ++r2) {
            int r8 = w * 2 + r2;
            int i_loc = s * 8 + r8;
            int i = i_base + i_loc;
#pragma unroll
            for (int hh = 0; hh < HH; ++hh) {
                float siv = si[(size_t)(b * HH + hh) * NN + i];
                float m = siv + smaxS[hh];
                m = (m >= 0.f) ? m : 0.2f * m;
                float z = 0.f;
                for (int jj = lane; jj < KSEL; jj += 64) {
                    int j = idxS[hh][jj];
                    float av = adjbuf[r8][j];
                    float e = siv + sjS[hh][jj];
                    e = (e >= 0.f) ? e : 0.2f * e;
                    float c = __expf(e - m);
                    z += c;
                    PS[hh][i_loc][jj] = f2bf(c * av);
                }
#pragma unroll
                for (int off = 32; off >= 1; off >>= 1) z += __shfl_xor(z, off);
                if (lane == 0) invZ[hh][i_loc] = 1.0f / z;
            }
        }
        __syncthreads();
    }
    // Phase 2: wave w computes head w's 32x32 output via MFMA
    float4v acc[2][2];
#pragma unroll
    for (int mi = 0; mi < 2; ++mi)
#pragma unroll
        for (int ni = 0; ni < 2; ++ni)
            acc[mi][ni] = (float4v){0.f, 0.f, 0.f, 0.f};
#pragma unroll
    for (int ks = 0; ks < 8; ++ks) {
#pragma unroll
        for (int mi = 0; mi < 2; ++mi) {
            short8 afr = *(const short8*)&PS[w][mi * 16 + mr][ks * 32 + quad * 8];
#pragma unroll
            for (int ni = 0; ni < 2; ++ni)
                acc[mi][ni] = __builtin_amdgcn_mfma_f32_16x16x32_bf16(afr, bfr[ni][ks], acc[mi][ni], 0, 0, 0);
        }
    }
#pragma unroll
    for (int mi = 0; mi < 2; ++mi)
#pragma unroll
        for (int ni = 0; ni < 2; ++ni)
#pragma unroll
            for (int r = 0; r < 4; ++r) {
                int i_loc = mi * 16 + quad * 4 + r;
                int d = ni * 16 + mr;
                int rowg = i_base + i_loc;
                out[((size_t)(b * NN + rowg)) * (HH * HD) + w * HD + d] =
                    acc[mi][ni][r] * invZ[w][i_loc];
            }
}

// ---------------------------------------------------------------------------
extern "C" void kernel_launch(void* const* d_in, const int* in_sizes, int n_in,
                              void* d_out, int out_size, void* d_ws, size_t ws_size,
                              hipStream_t stream) {
    const float* h   = (const float*)d_in[0];   // [B,N,DIN]
    const float* adj = (const float*)d_in[1];   // [B,N,N]
    const float* W   = (const float*)d_in[2];   // [H,DIN,HD]
    const float* a   = (const float*)d_in[3];   // [H,2*HD]
    float* out = (float*)d_out;                 // [B,N,H*HD]

    float* si     = (float*)d_ws;                        // BH*NN f32
    float* sj     = si + (size_t)BH * NN;                // BH*NN
    float* sjsel  = sj + (size_t)BH * NN;                // BH*KSEL
    float* sjmax  = sjsel + (size_t)BH * KSEL;           // BH (+pad)
    int*   idxsel = (int*)(sjmax + 16);                  // BH*KSEL
    int*   rank   = idxsel + (size_t)BH * KSEL;          // BH*NN
    short* hbf    = (short*)(rank + (size_t)BH * NN);    // BB*NN*DIN bf16
    short* Whg    = hbf + (size_t)BB * NN * DIN;         // BH*NN*HD bf16
    short* Whsel  = Whg + (size_t)BH * NN * HD;          // BH*HD*KPAD bf16

    hcvt_kernel<<<(BB * NN * DIN) / 1024, 256, 0, stream>>>(h, hbf);
    s_kernel<<<BH * 8, 256, 0, stream>>>(h, W, a, si, sj, rank);
    wh_kernel<<<BH * 16, 256, 0, stream>>>(hbf, W, Whg);
    rankp_kernel<<<BH * 16, 256, 0, stream>>>(sj, rank);
    compact_kernel<<<BH, 256, 0, stream>>>(sj, rank, Whg, idxsel, sjsel, sjmax, Whsel);
    attn_kernel<<<BB * 64, 256, 0, stream>>>(adj, Whsel, si, idxsel, sjsel, sjmax, out);
}

// Round 4
// 171.032 us; speedup vs baseline: 1.2212x; 1.2212x over previous
//
#include <hip/hip_runtime.h>
#include <hip/hip_bf16.h>
#include <cmath>

#define BB 4
#define NN 2048
#define DIN 128
#define HH 4
#define HD 32
#define KSEL 204            // int(0.1 * 2048)
#define BH (BB*HH)
#define KPAD 256            // K padded to 8 MFMA steps of 32
#define RPB 4               // rows per coef block

typedef __attribute__((ext_vector_type(8))) short short8;
typedef __attribute__((ext_vector_type(4))) short short4v;
typedef __attribute__((ext_vector_type(4))) float float4v;

static __device__ inline short f2bf(float x) {
    __hip_bfloat16 b = __float2bfloat16(x);   // RNE
    return __builtin_bit_cast(short, b);
}

// ---------------------------------------------------------------------------
// K0: h (f32) -> hbf (bf16), coalesced. 1M elems, 4 per thread.
__global__ __launch_bounds__(256) void hcvt_kernel(const float* __restrict__ h,
                                                   short* __restrict__ hbf) {
    int tid = blockIdx.x * 256 + threadIdx.x;
    float4 x = ((const float4*)h)[tid];
    short4v r;
    r[0] = f2bf(x.x); r[1] = f2bf(x.y); r[2] = f2bf(x.z); r[3] = f2bf(x.w);
    *(short4v*)(hbf + (size_t)tid * 4) = r;
}

// ---------------------------------------------------------------------------
// K1: s_i = h.(W@a1), s_j = h.(W@a2)  (all-f32 exact; feeds top-k). Zeroes rank.
__global__ __launch_bounds__(256) void s_kernel(const float* __restrict__ h,
                                                const float* __restrict__ W,
                                                const float* __restrict__ a,
                                                float* __restrict__ si, float* __restrict__ sj,
                                                int* __restrict__ rank) {
    int bh = blockIdx.x >> 3, chunk = blockIdx.x & 7;
    int b = bh >> 2, hh = bh & 3;
    __shared__ float w1[128], w2[128];
    int t = threadIdx.x;
    {   // wa = W[hh] @ a-halves, computed in-block
        int f = t & 127, half = t >> 7;
        const float* Wp = W + (size_t)hh * (DIN * HD) + f * HD;
        const float* ap = a + hh * 64 + half * 32;
        float acc = 0.f;
#pragma unroll
        for (int d = 0; d < 32; ++d) acc += Wp[d] * ap[d];
        if (half == 0) w1[f] = acc; else w2[f] = acc;
    }
    __syncthreads();
    int n = chunk * 256 + t;
    const float4* hr = (const float4*)(h + ((size_t)b * NN + n) * DIN);
    float s1 = 0.f, s2 = 0.f;
#pragma unroll 8
    for (int q = 0; q < 32; ++q) {
        float4 x = hr[q];
        s1 += x.x * w1[q*4] + x.y * w1[q*4+1] + x.z * w1[q*4+2] + x.w * w1[q*4+3];
        s2 += x.x * w2[q*4] + x.y * w2[q*4+1] + x.z * w2[q*4+2] + x.w * w2[q*4+3];
    }
    int o = bh * NN + n;
    si[o] = s1; sj[o] = s2; rank[o] = 0;
}

// ---------------------------------------------------------------------------
// K2: Whg[bh][n][d] (bf16) = hbf[b][n][:] @ W[h][:][d]  via MFMA 16x16x32 bf16
__global__ __launch_bounds__(256) void wh_kernel(const short* __restrict__ hbf,
                                                 const float* __restrict__ W,
                                                 short* __restrict__ Whg) {
    int bh = blockIdx.x >> 4, rtile = blockIdx.x & 15;
    int b = bh >> 2, hh = bh & 3;
    __shared__ short WT[32][136];   // WT[n][k] = bf16(W[hh][k][n])
    int t = threadIdx.x;
    for (int e = t; e < 32 * 128; e += 256) {
        int n = e >> 7, k = e & 127;
        WT[n][k] = f2bf(W[(size_t)hh * (DIN * HD) + k * HD + n]);
    }
    __syncthreads();
    int w = t >> 6, lane = t & 63, mr = lane & 15, quad = lane >> 4;
    int row_base = rtile * 128;
#pragma unroll
    for (int q = 0; q < 4; ++q) {
        int tt = w * 4 + q;
        int rt = tt >> 1, ct = tt & 1;
        int row0 = row_base + rt * 16;
        const short* hrow = hbf + ((size_t)b * NN + row0 + mr) * DIN + quad * 8;
        float4v acc = {0.f, 0.f, 0.f, 0.f};
#pragma unroll
        for (int ks = 0; ks < 4; ++ks) {
            short8 afr = *(const short8*)(hrow + ks * 32);
            short8 bfr = *(const short8*)&WT[ct * 16 + mr][ks * 32 + quad * 8];
            acc = __builtin_amdgcn_mfma_f32_16x16x32_bf16(afr, bfr, acc, 0, 0, 0);
        }
#pragma unroll
        for (int r = 0; r < 4; ++r) {
            int rowg = row0 + quad * 4 + r;
            Whg[((size_t)bh * NN + rowg) * HD + ct * 16 + mr] = f2bf(acc[r]);
        }
    }
}

// ---------------------------------------------------------------------------
// K3: partial rank counts. grid = BH*16; block handles 128 jp's vs all 2048 j's.
__global__ __launch_bounds__(256) void rankp_kernel(const float* __restrict__ sj,
                                                    int* __restrict__ rank) {
    int bh = blockIdx.x >> 4, jpc = blockIdx.x & 15;
    __shared__ float sv[128];
    int t = threadIdx.x;
    if (t < 128) sv[t] = sj[bh * NN + jpc * 128 + t];
    __syncthreads();
    int j0 = t * 8;
    const float* sjb = sj + bh * NN;
    float v[8]; int cnt[8];
#pragma unroll
    for (int r = 0; r < 8; ++r) { v[r] = sjb[j0 + r]; cnt[r] = 0; }
    int jpbase = jpc * 128;
    for (int jp = 0; jp < 128; ++jp) {
        float x = sv[jp];
        int jg = jpbase + jp;
#pragma unroll
        for (int r = 0; r < 8; ++r)
            cnt[r] += (x > v[r]) ? 1 : ((x == v[r] && jg < j0 + r) ? 1 : 0);
    }
#pragma unroll
    for (int r = 0; r < 8; ++r) atomicAdd(&rank[bh * NN + j0 + r], cnt[r]);
}

// ---------------------------------------------------------------------------
// K4: compact selected (rank < KSEL) ascending; sjsel + max; ALSO stage
// Whsel[bh][d][jj] bf16 (zero-padded K to 256) for pv B-fragments.
__global__ __launch_bounds__(256) void compact_kernel(const float* __restrict__ sj,
                                                      const int* __restrict__ rank,
                                                      const short* __restrict__ Whg,
                                                      int* __restrict__ idxsel,
                                                      float* __restrict__ sjsel,
                                                      float* __restrict__ sjmax,
                                                      short* __restrict__ Whsel) {
    int bh = blockIdx.x;
    int t = threadIdx.x, lane = t & 63, w = t >> 6;
    const int base = bh * NN;
    __shared__ int idxLDS[KSEL];
    int flags[8], cnt = 0;
    float lmax = -1e30f;
    int j0 = t * 8;
#pragma unroll
    for (int r = 0; r < 8; ++r) {
        int j = j0 + r;
        int f = (rank[base + j] < KSEL) ? 1 : 0;
        flags[r] = f; cnt += f;
        lmax = fmaxf(lmax, sj[base + j]);
    }
    int sc = cnt;
#pragma unroll
    for (int off = 1; off < 64; off <<= 1) {
        int u = __shfl_up(sc, off);
        if (lane >= off) sc += u;
    }
    float mx = lmax;
#pragma unroll
    for (int off = 32; off >= 1; off >>= 1) mx = fmaxf(mx, __shfl_xor(mx, off));
    __shared__ int wtot[4], woff[4];
    __shared__ float wmax[4];
    if (lane == 63) wtot[w] = sc;
    if (lane == 0) wmax[w] = mx;
    __syncthreads();
    if (t == 0) {
        int run = 0;
        for (int i = 0; i < 4; ++i) { woff[i] = run; run += wtot[i]; }
        sjmax[bh] = fmaxf(fmaxf(wmax[0], wmax[1]), fmaxf(wmax[2], wmax[3]));
    }
    __syncthreads();
    int pos = woff[w] + sc - cnt;
#pragma unroll
    for (int r = 0; r < 8; ++r) {
        if (flags[r]) {
            int j = j0 + r;
            idxsel[bh * KSEL + pos] = j;
            sjsel[bh * KSEL + pos] = sj[base + j];
            idxLDS[pos] = j;
            pos++;
        }
    }
    __syncthreads();
    // Whsel[bh][d][jj]: B-operand layout, contiguous jj, zero K-tail
    for (int e = t; e < HD * KPAD; e += 256) {
        int d = e >> 8, jj = e & 255;
        short v = 0;
        if (jj < KSEL) v = Whg[((size_t)bh * NN + idxLDS[jj]) * HD + d];
        Whsel[((size_t)bh * HD + d) * KPAD + jj] = v;
    }
}

// ---------------------------------------------------------------------------
// K5a: coefficients. Block = (b, RPB rows, 4 heads-as-waves). adj rows loaded
// DENSE into double-buffered LDS, shared by all 4 heads; P = exp*adj/z in bf16
// written to PS[bh][i][0..255] (tail zero). High occupancy (~23 KB LDS).
__global__ __launch_bounds__(256) void coef_kernel(
        const float* __restrict__ adj, const float* __restrict__ si,
        const int* __restrict__ idxsel, const float* __restrict__ sjsel,
        const float* __restrict__ sjmax, short* __restrict__ PS) {
    int b = blockIdx.x >> 9;          // 4
    int chunk = blockIdx.x & 511;     // 512 chunks of RPB=4 rows
    __shared__ float adjbuf[2][NN];
    __shared__ int   idxS[HH][KSEL];
    __shared__ float sjS[HH][KSEL];
    __shared__ float smaxS[HH];
    int t = threadIdx.x, w = t >> 6, lane = t & 63;
    for (int e = t; e < HH * KSEL; e += 256) {
        int hh = e / KSEL, jj = e - hh * KSEL;
        idxS[hh][jj] = idxsel[(b * HH + hh) * KSEL + jj];
        sjS[hh][jj]  = sjsel[(b * HH + hh) * KSEL + jj];
    }
    if (t < HH) smaxS[t] = sjmax[b * HH + t];
    int i0 = chunk * RPB;
    const float* adjb = adj + (size_t)b * NN * NN;
    // stage row 0
    {
        const float4* src = (const float4*)(adjb + (size_t)i0 * NN);
        ((float4*)adjbuf[0])[t]       = src[t];
        ((float4*)adjbuf[0])[t + 256] = src[t + 256];
    }
    __syncthreads();
    int bh = b * HH + w;
    float smax = smaxS[w];
    for (int r = 0; r < RPB; ++r) {
        // prefetch next row into registers (no LDS write yet)
        float4 p0, p1;
        if (r + 1 < RPB) {
            const float4* src = (const float4*)(adjb + (size_t)(i0 + r + 1) * NN);
            p0 = src[t]; p1 = src[t + 256];
        }
        const float* ab = adjbuf[r & 1];
        int i = i0 + r;
        float siv = si[(size_t)bh * NN + i];
        float m = siv + smax;
        m = (m >= 0.f) ? m : 0.2f * m;
        float pc[4], pa[4];
        float z = 0.f;
#pragma unroll
        for (int k = 0; k < 4; ++k) {
            int jj = k * 64 + lane;
            bool valid = jj < KSEL;
            int j = valid ? idxS[w][jj] : 0;
            float av = ab[j];
            float e = siv + (valid ? sjS[w][jj] : 0.f);
            e = (e >= 0.f) ? e : 0.2f * e;
            float c = valid ? __expf(e - m) : 0.f;
            z += c;
            pc[k] = c; pa[k] = av;
        }
#pragma unroll
        for (int off = 32; off >= 1; off >>= 1) z += __shfl_xor(z, off);
        float invz = 1.0f / z;
        short* prow = PS + ((size_t)bh * NN + i) * KPAD;
#pragma unroll
        for (int k = 0; k < 4; ++k) {
            int jj = k * 64 + lane;
            prow[jj] = f2bf(pc[k] * pa[k] * invz);   // tail lanes: pc=0 -> 0
        }
        // write prefetched row AFTER compute, then barrier
        if (r + 1 < RPB) {
            float4* dst = (float4*)adjbuf[(r + 1) & 1];
            dst[t] = p0; dst[t + 256] = p1;
        }
        __syncthreads();
    }
}

// ---------------------------------------------------------------------------
// K5b: out = P @ Whsel via MFMA. No LDS; A/B fragments straight from global
// (64B-line-aligned per 16-lane group). Block = (bh, 32-row tile), 4 waves.
__global__ __launch_bounds__(256) void pv_kernel(
        const short* __restrict__ PS, const short* __restrict__ Whsel,
        float* __restrict__ out) {
    int bh = blockIdx.x >> 6, tile = blockIdx.x & 63;
    int b = bh >> 2, hh = bh & 3;
    int t = threadIdx.x, w = t >> 6, lane = t & 63;
    int mr = lane & 15, quad = lane >> 4;
    int mi = w >> 1, ni = w & 1;
    int i0 = tile * 32;
    const short* pA = PS + ((size_t)bh * NN + i0 + mi * 16 + mr) * KPAD + quad * 8;
    const short* pB = Whsel + ((size_t)bh * HD + ni * 16 + mr) * KPAD + quad * 8;
    float4v acc = {0.f, 0.f, 0.f, 0.f};
#pragma unroll
    for (int ks = 0; ks < 8; ++ks) {
        short8 afr = *(const short8*)(pA + ks * 32);
        short8 bfr = *(const short8*)(pB + ks * 32);
        acc = __builtin_amdgcn_mfma_f32_16x16x32_bf16(afr, bfr, acc, 0, 0, 0);
    }
#pragma unroll
    for (int r = 0; r < 4; ++r) {
        int i = i0 + mi * 16 + quad * 4 + r;
        int d = ni * 16 + mr;
        out[((size_t)(b * NN + i)) * (HH * HD) + hh * HD + d] = acc[r];
    }
}

// ---------------------------------------------------------------------------
extern "C" void kernel_launch(void* const* d_in, const int* in_sizes, int n_in,
                              void* d_out, int out_size, void* d_ws, size_t ws_size,
                              hipStream_t stream) {
    const float* h   = (const float*)d_in[0];   // [B,N,DIN]
    const float* adj = (const float*)d_in[1];   // [B,N,N]
    const float* W   = (const float*)d_in[2];   // [H,DIN,HD]
    const float* a   = (const float*)d_in[3];   // [H,2*HD]
    float* out = (float*)d_out;                 // [B,N,H*HD]

    float* si     = (float*)d_ws;                        // BH*NN f32
    float* sj     = si + (size_t)BH * NN;                // BH*NN
    float* sjsel  = sj + (size_t)BH * NN;                // BH*KSEL
    float* sjmax  = sjsel + (size_t)BH * KSEL;           // BH (pad 16)
    int*   idxsel = (int*)(sjmax + 16);                  // BH*KSEL
    int*   rank   = idxsel + (size_t)BH * KSEL;          // BH*NN
    short* hbf    = (short*)(rank + (size_t)BH * NN);    // BB*NN*DIN bf16
    short* Whg    = hbf + (size_t)BB * NN * DIN;         // BH*NN*HD bf16
    short* Whsel  = Whg + (size_t)BH * NN * HD;          // BH*HD*KPAD bf16
    short* PS     = Whsel + (size_t)BH * HD * KPAD;      // BH*NN*KPAD bf16

    hcvt_kernel<<<(BB * NN * DIN) / 1024, 256, 0, stream>>>(h, hbf);
    s_kernel<<<BH * 8, 256, 0, stream>>>(h, W, a, si, sj, rank);
    wh_kernel<<<BH * 16, 256, 0, stream>>>(hbf, W, Whg);
    rankp_kernel<<<BH * 16, 256, 0, stream>>>(sj, rank);
    compact_kernel<<<BH, 256, 0, stream>>>(sj, rank, Whg, idxsel, sjsel, sjmax, Whsel);
    coef_kernel<<<BB * (NN / RPB), 256, 0, stream>>>(adj, si, idxsel, sjsel, sjmax, PS);
    pv_kernel<<<BH * 64, 256, 0, stream>>>(PS, Whsel, out);
}